// Round 2
// baseline (339.741 us; speedup 1.0000x reference)
//
#include <hip/hip_runtime.h>
#include <math.h>

#define BSAMP 4096
#define D_IN  768
#define D_OUT 1024
#define NEXP  10
#define LN_EPS 1e-5f
#define KT1 (D_IN / 32)    // 24
#define KT2 (D_OUT / 32)   // 32

typedef __attribute__((ext_vector_type(8))) short bf16x8;
typedef __attribute__((ext_vector_type(4))) float f32x4;

__device__ __forceinline__ float b2f(unsigned short u) {
    union { unsigned int i; float f; } v; v.i = ((unsigned int)u) << 16; return v.f;
}
__device__ __forceinline__ unsigned short f2b(float f) {
    union { float f; unsigned int i; } v; v.f = f;
    unsigned int x = v.i;
    unsigned int r = (x + 0x7fffu + ((x >> 16) & 1u)) >> 16;   // RNE
    return (unsigned short)r;
}

// ---------------- routing ----------------

__global__ void k4_init(int* counts, int* cursor) {
    int t = threadIdx.x;
    if (t < 16) { counts[t] = 0; cursor[t] = 0; }
}

__global__ void k4_router(const float* __restrict__ logits,
                          int* __restrict__ cls, int* __restrict__ counts,
                          float* __restrict__ out1) {
    int b = blockIdx.x * 256 + threadIdx.x;
    if (b >= BSAMP) return;
    const float* L = logits + (size_t)b * NEXP;
    float best = L[0]; int be = 0;
    #pragma unroll
    for (int e = 0; e < NEXP; e++) {
        float v = L[e];
        out1[(size_t)b * NEXP + e] = v;          // f32 bit-exact passthrough
        if (v > best) { best = v; be = e; }      // strict > == first-max (jnp.argmax)
    }
    cls[b] = be;
    atomicAdd(&counts[be], 1);
}

__global__ void k4_scan(const int* counts, int* offs, int* cursor) {
    if (threadIdx.x == 0) {
        int s = 0;
        for (int e = 0; e < NEXP; e++) { offs[e] = s; cursor[e] = s; s += counts[e]; }
        offs[NEXP] = s;
    }
}

__global__ void k4_scatter(const int* __restrict__ cls, int* __restrict__ cursor,
                           int* __restrict__ idx) {
    int b = blockIdx.x * 256 + threadIdx.x;
    if (b >= BSAMP) return;
    int p = atomicAdd(&cursor[cls[b]], 1);
    idx[p] = b;
}

// ---------------- x: f32 -> bf16, flat ----------------
__global__ __launch_bounds__(256)
void k5_xcvt(const float* __restrict__ X, unsigned short* __restrict__ xb) {
    int i = (blockIdx.x * 256 + threadIdx.x) * 8;
    float4 v0 = *(const float4*)(X + i);
    float4 v1 = *(const float4*)(X + i + 4);
    unsigned short t[8] = { f2b(v0.x), f2b(v0.y), f2b(v0.z), f2b(v0.w),
                            f2b(v1.x), f2b(v1.y), f2b(v1.z), f2b(v1.w) };
    *(bf16x8*)(xb + i) = *(bf16x8*)t;
}

// ---------------- weight convert+transpose: W[e][k][n] f32 -> tiled bf16 ----------------
// Wt tile layout: [e][nt(=n>>7)][kt(=k>>5)][nn(128)][kk(32)], tile = 4096 elems = 8 KB.
__global__ __launch_bounds__(256)
void k4_cvt(const float* __restrict__ W, unsigned short* __restrict__ Wt, int K) {
    const int t  = threadIdx.x;
    const int kt = blockIdx.x;          // K/32
    const int e  = blockIdx.z;
    const int n  = blockIdx.y * 256 + t;
    const int KT = K >> 5;
    const float* src = W + ((size_t)e * K + (size_t)kt * 32) * D_OUT + n;
    unsigned short v[32];
    #pragma unroll
    for (int j = 0; j < 32; j++) v[j] = f2b(src[(size_t)j * D_OUT]);
    const int nt = n >> 7, nn = n & 127;
    unsigned short* dst = Wt + ((((size_t)e * 8 + nt) * KT + kt) << 12) + nn * 32;
    #pragma unroll
    for (int j = 0; j < 4; j++)
        *(bf16x8*)&dst[j * 8] = *(bf16x8*)&v[j * 8];
}

// ---------------- GEMM core: 32x32 wave tile, 4-slot ring, prefetch distance 3 ----------
// Aa[i]/Bb[i] buffer indices are LITERAL constants everywhere (no scratch).
// Over-reads at the K-tail (up to step KT+2) are absorbed by workspace layout slack.

#define LOADSTEP(i, s) do { \
    Aa##i##0 = *(const bf16x8*)(aPtr0 + (s) * 32); \
    Aa##i##1 = *(const bf16x8*)(aPtr1 + (s) * 32); \
    const unsigned short* bp_ = bB + (size_t)(s) * 4096; \
    Bb##i##0 = *(const bf16x8*)(bp_); \
    Bb##i##1 = *(const bf16x8*)(bp_ + 512); \
} while (0)

#define MM4(i) \
    acc[0][0] = __builtin_amdgcn_mfma_f32_16x16x32_bf16(Aa##i##0, Bb##i##0, acc[0][0], 0, 0, 0); \
    acc[0][1] = __builtin_amdgcn_mfma_f32_16x16x32_bf16(Aa##i##0, Bb##i##1, acc[0][1], 0, 0, 0); \
    acc[1][0] = __builtin_amdgcn_mfma_f32_16x16x32_bf16(Aa##i##1, Bb##i##0, acc[1][0], 0, 0, 0); \
    acc[1][1] = __builtin_amdgcn_mfma_f32_16x16x32_bf16(Aa##i##1, Bb##i##1, acc[1][1], 0, 0, 0);

#define GEMM_PIPE(KT) \
    bf16x8 Aa00, Aa01, Aa10, Aa11, Aa20, Aa21, Aa30, Aa31; \
    bf16x8 Bb00, Bb01, Bb10, Bb11, Bb20, Bb21, Bb30, Bb31; \
    LOADSTEP(0, 0); LOADSTEP(1, 1); LOADSTEP(2, 2); \
    for (int kt = 0; kt < KT; kt += 4) { \
        LOADSTEP(3, kt + 3); \
        MM4(0); \
        LOADSTEP(0, kt + 4); \
        MM4(1); \
        LOADSTEP(1, kt + 5); \
        MM4(2); \
        LOADSTEP(2, kt + 6); \
        MM4(3); \
    }

// ---------------- GEMM1: e1g/g1g[p][n] from xb[idx[p]] @ W1[e] ----------------
// block = 32 rows x 128 cols, 4 waves, wave tile 32x32.
__global__ __launch_bounds__(256, 4)
void k5_gemm1(const unsigned short* __restrict__ xb, const unsigned short* __restrict__ W1t,
              const int* __restrict__ offs, const int* __restrict__ idx,
              unsigned short* __restrict__ e1g, unsigned short* __restrict__ g1g) {
    const int e = blockIdx.z;
    const int rowStart = offs[e] + blockIdx.y * 32;
    const int rowEnd = offs[e + 1];
    if (rowStart >= rowEnd) return;
    const int nt = blockIdx.x;

    const int tid  = threadIdx.x;
    const int lane = tid & 63;
    const int wv   = __builtin_amdgcn_readfirstlane(tid >> 6);
    const int quad = lane >> 4;
    const int l16  = lane & 15;

    int p0 = rowStart + l16;
    int p1 = p0 + 16;
    const unsigned short* aPtr0 = xb + (size_t)idx[p0 < rowEnd ? p0 : rowEnd - 1] * D_IN + quad * 8;
    const unsigned short* aPtr1 = xb + (size_t)idx[p1 < rowEnd ? p1 : rowEnd - 1] * D_IN + quad * 8;
    // B: tile base (uniform) + wave col (uniform) + lane offset
    const unsigned short* bB = W1t + ((((size_t)e * 8 + nt) * KT1) << 12)
                             + (size_t)wv * 1024 + l16 * 32 + quad * 8;

    f32x4 acc[2][2];
    const f32x4 zf = {0.f, 0.f, 0.f, 0.f};
    #pragma unroll
    for (int r = 0; r < 2; r++)
        #pragma unroll
        for (int c = 0; c < 2; c++) acc[r][c] = zf;

    GEMM_PIPE(KT1);

    // C/D: col = l16, row = quad*4 + q. Write raw bf16 + gelu'd bf16 (grouped rows).
    const int n0 = nt * 128 + wv * 32;
    #pragma unroll
    for (int r = 0; r < 2; r++)
        #pragma unroll
        for (int q = 0; q < 4; q++) {
            int pp = rowStart + r * 16 + quad * 4 + q;
            if (pp < rowEnd) {
                unsigned short* ep = e1g + (size_t)pp * D_OUT + n0 + l16;
                unsigned short* gp = g1g + (size_t)pp * D_OUT + n0 + l16;
                #pragma unroll
                for (int c = 0; c < 2; c++) {
                    unsigned short vb = f2b(acc[r][c][q]);
                    ep[c * 16] = vb;
                    float v = b2f(vb);
                    gp[c * 16] = f2b(v / (1.0f + __expf(-1.702f * v)));
                }
            }
        }
}

// ---------------- GEMM2: out0[idx[p]][n] = f32( g1g @ W2 + e1g ) ----------------
__global__ __launch_bounds__(256, 4)
void k5_gemm2(const unsigned short* __restrict__ g1g, const unsigned short* __restrict__ e1g,
              const unsigned short* __restrict__ W2t,
              const int* __restrict__ offs, const int* __restrict__ idx,
              float* __restrict__ out0) {
    const int e = blockIdx.z;
    const int rowStart = offs[e] + blockIdx.y * 32;
    const int rowEnd = offs[e + 1];
    if (rowStart >= rowEnd) return;
    const int nt = blockIdx.x;

    const int tid  = threadIdx.x;
    const int lane = tid & 63;
    const int wv   = __builtin_amdgcn_readfirstlane(tid >> 6);
    const int quad = lane >> 4;
    const int l16  = lane & 15;

    int p0 = rowStart + l16;
    int p1 = p0 + 16;
    const unsigned short* aPtr0 = g1g + (size_t)(p0 < rowEnd ? p0 : rowEnd - 1) * D_OUT + quad * 8;
    const unsigned short* aPtr1 = g1g + (size_t)(p1 < rowEnd ? p1 : rowEnd - 1) * D_OUT + quad * 8;
    const unsigned short* bB = W2t + ((((size_t)e * 8 + nt) * KT2) << 12)
                             + (size_t)wv * 1024 + l16 * 32 + quad * 8;

    f32x4 acc[2][2];
    const f32x4 zf = {0.f, 0.f, 0.f, 0.f};
    #pragma unroll
    for (int r = 0; r < 2; r++)
        #pragma unroll
        for (int c = 0; c < 2; c++) acc[r][c] = zf;

    GEMM_PIPE(KT2);

    // epilogue: s = acc + e1 (residual), scatter f32 to original rows
    const int n0 = nt * 128 + wv * 32;
    #pragma unroll
    for (int r = 0; r < 2; r++)
        #pragma unroll
        for (int q = 0; q < 4; q++) {
            int pp = rowStart + r * 16 + quad * 4 + q;
            if (pp < rowEnd) {
                int orow = idx[pp];
                const unsigned short* ep = e1g + (size_t)pp * D_OUT + n0 + l16;
                float* op = out0 + (size_t)orow * D_OUT + n0 + l16;
                #pragma unroll
                for (int c = 0; c < 2; c++)
                    op[c * 16] = acc[r][c][q] + b2f(ep[c * 16]);
            }
        }
}

// ---------------- LN + L2, in place on out0; one wave per row ----------------
__global__ __launch_bounds__(256)
void k4_ln(float* __restrict__ out0, const int* __restrict__ cls,
           const float* __restrict__ gam, const float* __restrict__ bet) {
    const int wave = threadIdx.x >> 6;
    const int lane = threadIdx.x & 63;
    const int b = blockIdx.x * 4 + wave;
    const int e = cls[b];

    float* row = out0 + (size_t)b * D_OUT + lane * 16;
    float v[16];
    #pragma unroll
    for (int j = 0; j < 4; j++) {
        float4 t = *(const float4*)(row + j * 4);
        v[j*4] = t.x; v[j*4+1] = t.y; v[j*4+2] = t.z; v[j*4+3] = t.w;
    }

    float sum = 0.f, sq = 0.f;
    #pragma unroll
    for (int j = 0; j < 16; j++) { sum += v[j]; sq += v[j] * v[j]; }
    #pragma unroll
    for (int o = 32; o; o >>= 1) { sum += __shfl_xor(sum, o, 64); sq += __shfl_xor(sq, o, 64); }
    float mean = sum * (1.0f / 1024.0f);
    float var = sq * (1.0f / 1024.0f) - mean * mean;
    float inv = rsqrtf(var + LN_EPS);

    const float* gp = gam + (size_t)e * D_OUT + lane * 16;
    const float* bp = bet + (size_t)e * D_OUT + lane * 16;
    float y[16]; float y2 = 0.f;
    #pragma unroll
    for (int j = 0; j < 16; j++) {
        y[j] = (v[j] - mean) * inv * gp[j] + bp[j];
        y2 += y[j] * y[j];
    }
    #pragma unroll
    for (int o = 32; o; o >>= 1) y2 += __shfl_xor(y2, o, 64);
    float rn = rsqrtf(y2);

    #pragma unroll
    for (int j = 0; j < 4; j++) {
        float4 t = { y[j*4] * rn, y[j*4+1] * rn, y[j*4+2] * rn, y[j*4+3] * rn };
        *(float4*)(row + j * 4) = t;
    }
}

// ---------------- launch ----------------
extern "C" void kernel_launch(void* const* d_in, const int* in_sizes, int n_in,
                              void* d_out, int out_size, void* d_ws, size_t ws_size,
                              hipStream_t stream) {
    const float* x   = (const float*)d_in[0];
    const float* lg  = (const float*)d_in[1];
    const float* W1  = (const float*)d_in[2];
    const float* W2  = (const float*)d_in[3];
    const float* gam = (const float*)d_in[4];
    const float* bet = (const float*)d_in[5];
    float* out0 = (float*)d_out;
    float* out1 = out0 + (size_t)BSAMP * D_OUT;

    // ws layout (over-read-safe ordering — K-tail prefetch over-reads land in the
    // next buffer / Wt slack):
    //   [0,64K) control | e1g 8M | g1g 8M | xb 6M | Wt 21M (W1t/W2t sequential reuse,
    //   ~1MB internal slack past W2t end).  Total ~43.1 MB.
    char* ws = (char*)d_ws;
    int* counts = (int*)ws;            // 16
    int* offs   = counts + 16;         // 16
    int* cursor = offs + 16;           // 16
    int* cls    = cursor + 16;         // 4096
    int* idx    = cls + BSAMP;         // 4096
    unsigned short* e1g = (unsigned short*)(ws + 65536);
    unsigned short* g1g = e1g + (size_t)BSAMP * D_OUT;
    unsigned short* xb  = g1g + (size_t)BSAMP * D_OUT;
    unsigned short* Wt  = xb + (size_t)BSAMP * D_IN;

    k4_init<<<1, 64, 0, stream>>>(counts, cursor);
    k4_router<<<16, 256, 0, stream>>>(lg, cls, counts, out1);
    k4_scan<<<1, 64, 0, stream>>>(counts, offs, cursor);
    k4_scatter<<<16, 256, 0, stream>>>(cls, cursor, idx);

    // x -> bf16 once
    k5_xcvt<<<BSAMP * D_IN / (256 * 8), 256, 0, stream>>>(x, xb);

    // W1 -> tiled bf16, then GEMM1 (writes raw e1 and gelu(e1))
    dim3 gc1(D_IN / 32, 4, NEXP);
    k4_cvt<<<gc1, 256, 0, stream>>>(W1, Wt, D_IN);
    dim3 g1(8, 128, NEXP);
    k5_gemm1<<<g1, 256, 0, stream>>>(xb, Wt, offs, idx, e1g, g1g);

    // W2 -> tiled bf16 (reuses Wt region; stream-ordered after gemm1), then GEMM2
    dim3 gc2(D_OUT / 32, 4, NEXP);
    k4_cvt<<<gc2, 256, 0, stream>>>(W2, Wt, D_OUT);
    dim3 g2(8, 128, NEXP);
    k5_gemm2<<<g2, 256, 0, stream>>>(g1g, e1g, Wt, offs, idx, out0);

    k4_ln<<<BSAMP / 4, 256, 0, stream>>>(out0, cls, gam, bet);
}

// Round 3
// 244.400 us; speedup vs baseline: 1.3901x; 1.3901x over previous
//
#include <hip/hip_runtime.h>
#include <math.h>

#define BSAMP 4096
#define D_IN  768
#define D_OUT 1024
#define NEXP  10
#define LN_EPS 1e-5f
#define STEPS1 (D_IN / 64)    // 12
#define STEPS2 (D_OUT / 64)   // 16

typedef __attribute__((ext_vector_type(8))) short bf16x8;
typedef __attribute__((ext_vector_type(4))) float f32x4;

__device__ __forceinline__ float b2f(unsigned short u) {
    union { unsigned int i; float f; } v; v.i = ((unsigned int)u) << 16; return v.f;
}
__device__ __forceinline__ unsigned short f2b(float f) {
    union { float f; unsigned int i; } v; v.f = f;
    unsigned int x = v.i;
    unsigned int r = (x + 0x7fffu + ((x >> 16) & 1u)) >> 16;   // RNE
    return (unsigned short)r;
}

// ---------------- routing ----------------

__global__ void k4_init(int* counts, int* cursor) {
    int t = threadIdx.x;
    if (t < 16) { counts[t] = 0; cursor[t] = 0; }
}

__global__ void k4_router(const float* __restrict__ logits,
                          int* __restrict__ cls, int* __restrict__ counts,
                          float* __restrict__ out1) {
    int b = blockIdx.x * 256 + threadIdx.x;
    if (b >= BSAMP) return;
    const float* L = logits + (size_t)b * NEXP;
    float best = L[0]; int be = 0;
    #pragma unroll
    for (int e = 0; e < NEXP; e++) {
        float v = L[e];
        out1[(size_t)b * NEXP + e] = v;          // f32 bit-exact passthrough
        if (v > best) { best = v; be = e; }      // strict > == first-max (jnp.argmax)
    }
    cls[b] = be;
    atomicAdd(&counts[be], 1);
}

__global__ void k4_scan(const int* counts, int* offs, int* cursor) {
    if (threadIdx.x == 0) {
        int s = 0;
        for (int e = 0; e < NEXP; e++) { offs[e] = s; cursor[e] = s; s += counts[e]; }
        offs[NEXP] = s;
    }
}

__global__ void k4_scatter(const int* __restrict__ cls, int* __restrict__ cursor,
                           int* __restrict__ idx) {
    int b = blockIdx.x * 256 + threadIdx.x;
    if (b >= BSAMP) return;
    int p = atomicAdd(&cursor[cls[b]], 1);
    idx[p] = b;
}

// ---------------- x: f32 -> bf16, flat ----------------
__global__ __launch_bounds__(256)
void k5_xcvt(const float* __restrict__ X, unsigned short* __restrict__ xb) {
    int i = (blockIdx.x * 256 + threadIdx.x) * 8;
    float4 v0 = *(const float4*)(X + i);
    float4 v1 = *(const float4*)(X + i + 4);
    unsigned short t[8] = { f2b(v0.x), f2b(v0.y), f2b(v0.z), f2b(v0.w),
                            f2b(v1.x), f2b(v1.y), f2b(v1.z), f2b(v1.w) };
    *(bf16x8*)(xb + i) = *(bf16x8*)t;
}

// ---------------- weight convert+transpose: W[e][k][n] f32 -> tiled bf16 ----------------
// Wt tile layout: [e][nt(=n>>7)][kt(=k>>5)][nn(128)][kk(32)], tile = 4096 elems = 8 KB.
__global__ __launch_bounds__(256)
void k4_cvt(const float* __restrict__ W, unsigned short* __restrict__ Wt, int K) {
    const int t  = threadIdx.x;
    const int kt = blockIdx.x;          // K/32
    const int e  = blockIdx.z;
    const int n  = blockIdx.y * 256 + t;
    const int KT = K >> 5;
    const float* src = W + ((size_t)e * K + (size_t)kt * 32) * D_OUT + n;
    unsigned short v[32];
    #pragma unroll
    for (int j = 0; j < 32; j++) v[j] = f2b(src[(size_t)j * D_OUT]);
    const int nt = n >> 7, nn = n & 127;
    unsigned short* dst = Wt + ((((size_t)e * 8 + nt) * KT + kt) << 12) + nn * 32;
    #pragma unroll
    for (int j = 0; j < 4; j++)
        *(bf16x8*)&dst[j * 8] = *(bf16x8*)&v[j * 8];
}

// ---------------- GEMM: 64x128 tile, BK=64, 2-phase LDS double-buffer ----------------
// LDS layouts (conflict-free fragment reads, 256B-contiguous per 16-lane group):
//   A[kc(8)][m(64)][8]  (8 KB)   B[kc(8)][n(128)][8]  (16 KB)   x2 buffers = 48 KB.
// Staged via global_load_lds (dst = linear tid*16B); source addresses remapped per
// lane so content matches the layout (both-sides-or-neither rule).

#define GLDS(srcp, dstp) __builtin_amdgcn_global_load_lds( \
    (const __attribute__((address_space(1))) unsigned int*)(srcp), \
    (__attribute__((address_space(3))) unsigned int*)(dstp), 16, 0, 0)

// A: thread owns row m=tid&63; chunk j covers kc = (tid>>6) + j*4.
#define STAGE_A(Ab, t) do { \
    _Pragma("unroll") \
    for (int j = 0; j < 2; j++) { \
        int c = tid + j * 256; \
        GLDS(aRow + (t) * 64 + (c >> 6) * 8, (Ab) + c * 8); \
    } \
} while (0)

// B: chunk c -> kc=c>>7, n=c&127; source = cvt tile (kt32 = 2t + (kc>=4)), elem n*32+(kc&3)*8.
#define STAGE_B(Bb, t) do { \
    _Pragma("unroll") \
    for (int j = 0; j < 4; j++) { \
        int c = tid + j * 256; \
        int kc = c >> 7; \
        GLDS(bPanel + ((size_t)(2 * (t) + (kc >> 2)) << 12) + (c & 127) * 32 + (kc & 3) * 8, \
             (Bb) + c * 8); \
    } \
} while (0)

// 16 MFMA per K-step (2 k-substeps x 2 rows x 4 cols), fragments read conflict-free.
#define COMPUTE(Ab, Bb) do { \
    _Pragma("unroll") \
    for (int s = 0; s < 2; s++) { \
        const unsigned short* ab_ = (Ab) + (s * 4 + quad) * 512; \
        const unsigned short* bb_ = (Bb) + (s * 4 + quad) * 1024; \
        bf16x8 a0 = *(const bf16x8*)&ab_[(wrow + l16) * 8]; \
        bf16x8 a1 = *(const bf16x8*)&ab_[(wrow + 16 + l16) * 8]; \
        bf16x8 b0 = *(const bf16x8*)&bb_[(wcol + l16) * 8]; \
        bf16x8 b1 = *(const bf16x8*)&bb_[(wcol + 16 + l16) * 8]; \
        bf16x8 b2 = *(const bf16x8*)&bb_[(wcol + 32 + l16) * 8]; \
        bf16x8 b3 = *(const bf16x8*)&bb_[(wcol + 48 + l16) * 8]; \
        acc[0][0] = __builtin_amdgcn_mfma_f32_16x16x32_bf16(a0, b0, acc[0][0], 0, 0, 0); \
        acc[0][1] = __builtin_amdgcn_mfma_f32_16x16x32_bf16(a0, b1, acc[0][1], 0, 0, 0); \
        acc[0][2] = __builtin_amdgcn_mfma_f32_16x16x32_bf16(a0, b2, acc[0][2], 0, 0, 0); \
        acc[0][3] = __builtin_amdgcn_mfma_f32_16x16x32_bf16(a0, b3, acc[0][3], 0, 0, 0); \
        acc[1][0] = __builtin_amdgcn_mfma_f32_16x16x32_bf16(a1, b0, acc[1][0], 0, 0, 0); \
        acc[1][1] = __builtin_amdgcn_mfma_f32_16x16x32_bf16(a1, b1, acc[1][1], 0, 0, 0); \
        acc[1][2] = __builtin_amdgcn_mfma_f32_16x16x32_bf16(a1, b2, acc[1][2], 0, 0, 0); \
        acc[1][3] = __builtin_amdgcn_mfma_f32_16x16x32_bf16(a1, b3, acc[1][3], 0, 0, 0); \
    } \
} while (0)

// ---------------- GEMM1: e1g/g1g[p][n] = xb[idx[p]] @ W1[e] ----------------
__global__ __launch_bounds__(256)
void k6_gemm1(const unsigned short* __restrict__ xb, const unsigned short* __restrict__ W1t,
              const int* __restrict__ offs, const int* __restrict__ idx,
              unsigned short* __restrict__ e1g, unsigned short* __restrict__ g1g) {
    const int e = blockIdx.z;
    const int rowStart = offs[e] + blockIdx.y * 64;
    const int rowEnd = offs[e + 1];
    if (rowStart >= rowEnd) return;
    const int nt = blockIdx.x;

    __shared__ __align__(16) unsigned short A0[64 * 64], A1[64 * 64];     // 8 KB each
    __shared__ __align__(16) unsigned short B0[128 * 64], B1[128 * 64];   // 16 KB each
    __shared__ int rowIdxL[64];

    const int tid  = threadIdx.x;
    const int lane = tid & 63;
    const int wave = tid >> 6;
    const int quad = lane >> 4;
    const int l16  = lane & 15;
    const int wrow = (wave & 1) * 32;
    const int wcol = (wave >> 1) * 64;

    if (tid < 64) {
        int p = rowStart + tid;
        rowIdxL[tid] = idx[p < rowEnd ? p : rowEnd - 1];
    }
    __syncthreads();

    const unsigned short* aRow   = xb + (size_t)rowIdxL[tid & 63] * D_IN;
    const unsigned short* bPanel = W1t + ((((size_t)e * 8 + nt) * (D_IN / 32)) << 12);

    f32x4 acc[2][4];
    const f32x4 zf = {0.f, 0.f, 0.f, 0.f};
    #pragma unroll
    for (int r = 0; r < 2; r++)
        #pragma unroll
        for (int c = 0; c < 4; c++) acc[r][c] = zf;

    STAGE_A(A0, 0); STAGE_B(B0, 0);
    __syncthreads();
    for (int t = 0; t < STEPS1; t += 2) {
        STAGE_A(A1, t + 1); STAGE_B(B1, t + 1);   // prefetch next tile, then compute
        COMPUTE(A0, B0);
        __syncthreads();
        if (t + 2 < STEPS1) { STAGE_A(A0, t + 2); STAGE_B(B0, t + 2); }
        COMPUTE(A1, B1);
        __syncthreads();
    }

    // C/D: col = l16, row = quad*4 + q. Write raw bf16 + gelu'd bf16 (grouped rows).
    const int n0 = nt * 128;
    #pragma unroll
    for (int r = 0; r < 2; r++)
        #pragma unroll
        for (int q = 0; q < 4; q++) {
            int m = wrow + r * 16 + quad * 4 + q;
            int pp = rowStart + m;
            if (pp < rowEnd) {
                unsigned short* ep = e1g + (size_t)pp * D_OUT + n0 + wcol + l16;
                unsigned short* gp = g1g + (size_t)pp * D_OUT + n0 + wcol + l16;
                #pragma unroll
                for (int c = 0; c < 4; c++) {
                    unsigned short vb = f2b(acc[r][c][q]);
                    ep[c * 16] = vb;
                    float v = b2f(vb);
                    gp[c * 16] = f2b(v / (1.0f + __expf(-1.702f * v)));
                }
            }
        }
}

// ---------------- GEMM2: out0[idx[p]][n] = f32( g1g @ W2 + e1g ) ----------------
__global__ __launch_bounds__(256)
void k6_gemm2(const unsigned short* __restrict__ g1g, const unsigned short* __restrict__ e1g,
              const unsigned short* __restrict__ W2t,
              const int* __restrict__ offs, const int* __restrict__ idx,
              float* __restrict__ out0) {
    const int e = blockIdx.z;
    const int rowStart = offs[e] + blockIdx.y * 64;
    const int rowEnd = offs[e + 1];
    if (rowStart >= rowEnd) return;
    const int nt = blockIdx.x;

    __shared__ __align__(16) unsigned short A0[64 * 64], A1[64 * 64];
    __shared__ __align__(16) unsigned short B0[128 * 64], B1[128 * 64];
    __shared__ int rowIdxL[64];

    const int tid  = threadIdx.x;
    const int lane = tid & 63;
    const int wave = tid >> 6;
    const int quad = lane >> 4;
    const int l16  = lane & 15;
    const int wrow = (wave & 1) * 32;
    const int wcol = (wave >> 1) * 64;

    if (tid < 64) {
        int p = rowStart + tid;
        int ps = p < rowEnd ? p : rowEnd - 1;
        rowIdxL[tid] = idx[ps];
    }
    __syncthreads();

    int ap = rowStart + (tid & 63);
    const unsigned short* aRow   = g1g + (size_t)(ap < rowEnd ? ap : rowEnd - 1) * D_OUT;
    const unsigned short* bPanel = W2t + ((((size_t)e * 8 + nt) * (D_OUT / 32)) << 12);

    f32x4 acc[2][4];
    const f32x4 zf = {0.f, 0.f, 0.f, 0.f};
    #pragma unroll
    for (int r = 0; r < 2; r++)
        #pragma unroll
        for (int c = 0; c < 4; c++) acc[r][c] = zf;

    STAGE_A(A0, 0); STAGE_B(B0, 0);
    __syncthreads();
    for (int t = 0; t < STEPS2; t += 2) {
        STAGE_A(A1, t + 1); STAGE_B(B1, t + 1);
        COMPUTE(A0, B0);
        __syncthreads();
        if (t + 2 < STEPS2) { STAGE_A(A0, t + 2); STAGE_B(B0, t + 2); }
        COMPUTE(A1, B1);
        __syncthreads();
    }

    // epilogue: s = acc + e1 (residual), scatter f32 to original rows
    const int n0 = nt * 128;
    #pragma unroll
    for (int r = 0; r < 2; r++)
        #pragma unroll
        for (int q = 0; q < 4; q++) {
            int m = wrow + r * 16 + quad * 4 + q;
            int pp = rowStart + m;
            if (pp < rowEnd) {
                const unsigned short* ep = e1g + (size_t)pp * D_OUT + n0 + wcol + l16;
                float* op = out0 + (size_t)rowIdxL[m] * D_OUT + n0 + wcol + l16;
                #pragma unroll
                for (int c = 0; c < 4; c++)
                    op[c * 16] = acc[r][c][q] + b2f(ep[c * 16]);
            }
        }
}

// ---------------- LN + L2, in place on out0; one wave per row ----------------
__global__ __launch_bounds__(256)
void k4_ln(float* __restrict__ out0, const int* __restrict__ cls,
           const float* __restrict__ gam, const float* __restrict__ bet) {
    const int wave = threadIdx.x >> 6;
    const int lane = threadIdx.x & 63;
    const int b = blockIdx.x * 4 + wave;
    const int e = cls[b];

    float* row = out0 + (size_t)b * D_OUT + lane * 16;
    float v[16];
    #pragma unroll
    for (int j = 0; j < 4; j++) {
        float4 t = *(const float4*)(row + j * 4);
        v[j*4] = t.x; v[j*4+1] = t.y; v[j*4+2] = t.z; v[j*4+3] = t.w;
    }

    float sum = 0.f, sq = 0.f;
    #pragma unroll
    for (int j = 0; j < 16; j++) { sum += v[j]; sq += v[j] * v[j]; }
    #pragma unroll
    for (int o = 32; o; o >>= 1) { sum += __shfl_xor(sum, o, 64); sq += __shfl_xor(sq, o, 64); }
    float mean = sum * (1.0f / 1024.0f);
    float var = sq * (1.0f / 1024.0f) - mean * mean;
    float inv = rsqrtf(var + LN_EPS);

    const float* gp = gam + (size_t)e * D_OUT + lane * 16;
    const float* bp = bet + (size_t)e * D_OUT + lane * 16;
    float y[16]; float y2 = 0.f;
    #pragma unroll
    for (int j = 0; j < 16; j++) {
        y[j] = (v[j] - mean) * inv * gp[j] + bp[j];
        y2 += y[j] * y[j];
    }
    #pragma unroll
    for (int o = 32; o; o >>= 1) y2 += __shfl_xor(y2, o, 64);
    float rn = rsqrtf(y2);

    #pragma unroll
    for (int j = 0; j < 4; j++) {
        float4 t = { y[j*4] * rn, y[j*4+1] * rn, y[j*4+2] * rn, y[j*4+3] * rn };
        *(float4*)(row + j * 4) = t;
    }
}

// ---------------- launch ----------------
extern "C" void kernel_launch(void* const* d_in, const int* in_sizes, int n_in,
                              void* d_out, int out_size, void* d_ws, size_t ws_size,
                              hipStream_t stream) {
    const float* x   = (const float*)d_in[0];
    const float* lg  = (const float*)d_in[1];
    const float* W1  = (const float*)d_in[2];
    const float* W2  = (const float*)d_in[3];
    const float* gam = (const float*)d_in[4];
    const float* bet = (const float*)d_in[5];
    float* out0 = (float*)d_out;
    float* out1 = out0 + (size_t)BSAMP * D_OUT;

    // ws layout: [0,64K) control | Wt 21M (W1t/W2t sequential reuse) | e1g 8M
    //            | g1g 8M | xb 6M.  Total ~43.1 MB.
    char* ws = (char*)d_ws;
    int* counts = (int*)ws;            // 16
    int* offs   = counts + 16;         // 16
    int* cursor = offs + 16;           // 16
    int* cls    = cursor + 16;         // 4096
    int* idx    = cls + BSAMP;         // 4096
    unsigned short* Wt  = (unsigned short*)(ws + 65536);
    unsigned short* e1g = (unsigned short*)(ws + 65536 + 22020096);
    unsigned short* g1g = e1g + (size_t)BSAMP * D_OUT;
    unsigned short* xb  = g1g + (size_t)BSAMP * D_OUT;

    k4_init<<<1, 64, 0, stream>>>(counts, cursor);
    k4_router<<<16, 256, 0, stream>>>(lg, cls, counts, out1);
    k4_scan<<<1, 64, 0, stream>>>(counts, offs, cursor);
    k4_scatter<<<16, 256, 0, stream>>>(cls, cursor, idx);

    // x -> bf16 once (removes all f2b from gemm1 staging path)
    k5_xcvt<<<BSAMP * D_IN / (256 * 8), 256, 0, stream>>>(x, xb);

    // W1 -> tiled bf16, then GEMM1 (writes raw e1 and gelu(e1))
    dim3 gc1(D_IN / 32, 4, NEXP);
    k4_cvt<<<gc1, 256, 0, stream>>>(W1, Wt, D_IN);
    dim3 g1(8, 64, NEXP);
    k6_gemm1<<<g1, 256, 0, stream>>>(xb, Wt, offs, idx, e1g, g1g);

    // W2 -> tiled bf16 (reuses Wt region; stream-ordered after gemm1), then GEMM2
    dim3 gc2(D_OUT / 32, 4, NEXP);
    k4_cvt<<<gc2, 256, 0, stream>>>(W2, Wt, D_OUT);
    dim3 g2(8, 64, NEXP);
    k6_gemm2<<<g2, 256, 0, stream>>>(g1g, e1g, Wt, offs, idx, out0);

    k4_ln<<<BSAMP / 4, 256, 0, stream>>>(out0, cls, gam, bet);
}

// Round 4
// 209.828 us; speedup vs baseline: 1.6191x; 1.1648x over previous
//
#include <hip/hip_runtime.h>
#include <math.h>

#define BSAMP 4096
#define D_IN  768
#define D_OUT 1024
#define NEXP  10
#define LN_EPS 1e-5f
#define STEPS1 (D_IN / 64)    // 12
#define STEPS2 (D_OUT / 64)   // 16

// k7_prep block-range bounds
#define NB_CVT1 (D_IN / 32 * 4 * NEXP)    // 960
#define NB_CVT2 (D_OUT / 32 * 4 * NEXP)   // 1280
#define NB_XCVT (BSAMP * D_IN / 2048)     // 1536
#define NB_PREP (1 + NB_CVT1 + NB_CVT2 + NB_XCVT)   // 3777

typedef __attribute__((ext_vector_type(8))) short bf16x8;
typedef __attribute__((ext_vector_type(4))) float f32x4;

__device__ __forceinline__ float b2f(unsigned short u) {
    union { unsigned int i; float f; } v; v.i = ((unsigned int)u) << 16; return v.f;
}
__device__ __forceinline__ unsigned short f2b(float f) {
    union { float f; unsigned int i; } v; v.f = f;
    unsigned int x = v.i;
    unsigned int r = (x + 0x7fffu + ((x >> 16) & 1u)) >> 16;   // RNE
    return (unsigned short)r;
}

// ---------------- fused prep: routing + W1 cvt + W2 cvt + x cvt, ONE launch ----------

// weight convert+transpose body: W[e][k][n] f32 -> tiled bf16
// Wt tile layout: [e][nt(=n>>7)][kt(=k>>5)][nn(128)][kk(32)], tile = 4096 elems = 8 KB.
__device__ __forceinline__ void cvt_body(const float* __restrict__ W,
                                         unsigned short* __restrict__ Wt,
                                         int K, int i, int tid) {
    const int KT = K >> 5;
    const int kt = i % KT;
    const int rest = i / KT;
    const int n = (rest & 3) * 256 + tid;
    const int e = rest >> 2;
    const float* src = W + ((size_t)e * K + (size_t)kt * 32) * D_OUT + n;
    unsigned short v[32];
    #pragma unroll
    for (int j = 0; j < 32; j++) v[j] = f2b(src[(size_t)j * D_OUT]);
    const int nt = n >> 7, nn = n & 127;
    unsigned short* dst = Wt + ((((size_t)e * 8 + nt) * KT + kt) << 12) + nn * 32;
    #pragma unroll
    for (int j = 0; j < 4; j++)
        *(bf16x8*)&dst[j * 8] = *(bf16x8*)&v[j * 8];
}

__global__ __launch_bounds__(256)
void k7_prep(const float* __restrict__ logits, const float* __restrict__ X,
             const float* __restrict__ W1, const float* __restrict__ W2,
             float* __restrict__ out1, int* __restrict__ cls,
             int* __restrict__ idx, int* __restrict__ offs,
             unsigned short* __restrict__ xb, unsigned short* __restrict__ W1t,
             unsigned short* __restrict__ W2t) {
    const int tid = threadIdx.x;
    const int blk = blockIdx.x;

    if (blk == 0) {
        // ---- full routing pipeline in one block ----
        __shared__ int cnt[NEXP];
        __shared__ int cur[NEXP];
        __shared__ int offsL[NEXP + 1];
        if (tid < NEXP) cnt[tid] = 0;
        __syncthreads();

        int be[16];
        #pragma unroll
        for (int j = 0; j < 16; j++) {
            int b = tid + 256 * j;
            const float* L = logits + (size_t)b * NEXP;
            float best = L[0]; int e0 = 0;
            #pragma unroll
            for (int e = 0; e < NEXP; e++) {
                float v = L[e];
                out1[(size_t)b * NEXP + e] = v;          // f32 bit-exact passthrough
                if (v > best) { best = v; e0 = e; }      // strict > == first-max (jnp.argmax)
            }
            be[j] = e0;
            cls[b] = e0;
            atomicAdd(&cnt[e0], 1);
        }
        __syncthreads();
        if (tid == 0) {
            int s = 0;
            for (int e = 0; e < NEXP; e++) { offsL[e] = s; cur[e] = s; s += cnt[e]; }
            offsL[NEXP] = s;
        }
        __syncthreads();
        if (tid <= NEXP) offs[tid] = offsL[tid];
        #pragma unroll
        for (int j = 0; j < 16; j++) {
            int b = tid + 256 * j;
            int p = atomicAdd(&cur[be[j]], 1);
            idx[p] = b;
        }
        return;
    }

    int i = blk - 1;
    if (i < NB_CVT1) { cvt_body(W1, W1t, D_IN, i, tid); return; }
    i -= NB_CVT1;
    if (i < NB_CVT2) { cvt_body(W2, W2t, D_OUT, i, tid); return; }
    i -= NB_CVT2;
    {   // x: f32 -> bf16, flat
        int o = (i * 256 + tid) * 8;
        float4 v0 = *(const float4*)(X + o);
        float4 v1 = *(const float4*)(X + o + 4);
        unsigned short t[8] = { f2b(v0.x), f2b(v0.y), f2b(v0.z), f2b(v0.w),
                                f2b(v1.x), f2b(v1.y), f2b(v1.z), f2b(v1.w) };
        *(bf16x8*)(xb + o) = *(bf16x8*)t;
    }
}

// ---------------- GEMM: 64x128 tile, BK=64, 2-phase LDS double-buffer ----------------
// LDS layouts (conflict-free fragment reads, 256B-contiguous per 16-lane group):
//   A[kc(8)][m(64)][8]  (8 KB)   B[kc(8)][n(128)][8]  (16 KB)   x2 buffers = 48 KB.
// Staged via global_load_lds (dst = linear tid*16B); source addresses remapped per
// lane so content matches the layout (both-sides-or-neither rule).

#define GLDS(srcp, dstp) __builtin_amdgcn_global_load_lds( \
    (const __attribute__((address_space(1))) unsigned int*)(srcp), \
    (__attribute__((address_space(3))) unsigned int*)(dstp), 16, 0, 0)

// A: thread owns row m=tid&63; chunk j covers kc = (tid>>6) + j*4.
#define STAGE_A(Ab, t) do { \
    _Pragma("unroll") \
    for (int j = 0; j < 2; j++) { \
        int c = tid + j * 256; \
        GLDS(aRow + (t) * 64 + (c >> 6) * 8, (Ab) + c * 8); \
    } \
} while (0)

// B: chunk c -> kc=c>>7, n=c&127; source = cvt tile (kt32 = 2t + (kc>=4)), elem n*32+(kc&3)*8.
#define STAGE_B(Bb, t) do { \
    _Pragma("unroll") \
    for (int j = 0; j < 4; j++) { \
        int c = tid + j * 256; \
        int kc = c >> 7; \
        GLDS(bPanel + ((size_t)(2 * (t) + (kc >> 2)) << 12) + (c & 127) * 32 + (kc & 3) * 8, \
             (Bb) + c * 8); \
    } \
} while (0)

// 16 MFMA per K-step (2 k-substeps x 2 rows x 4 cols), fragments read conflict-free.
#define COMPUTE(Ab, Bb) do { \
    _Pragma("unroll") \
    for (int s = 0; s < 2; s++) { \
        const unsigned short* ab_ = (Ab) + (s * 4 + quad) * 512; \
        const unsigned short* bb_ = (Bb) + (s * 4 + quad) * 1024; \
        bf16x8 a0 = *(const bf16x8*)&ab_[(wrow + l16) * 8]; \
        bf16x8 a1 = *(const bf16x8*)&ab_[(wrow + 16 + l16) * 8]; \
        bf16x8 b0 = *(const bf16x8*)&bb_[(wcol + l16) * 8]; \
        bf16x8 b1 = *(const bf16x8*)&bb_[(wcol + 16 + l16) * 8]; \
        bf16x8 b2 = *(const bf16x8*)&bb_[(wcol + 32 + l16) * 8]; \
        bf16x8 b3 = *(const bf16x8*)&bb_[(wcol + 48 + l16) * 8]; \
        acc[0][0] = __builtin_amdgcn_mfma_f32_16x16x32_bf16(a0, b0, acc[0][0], 0, 0, 0); \
        acc[0][1] = __builtin_amdgcn_mfma_f32_16x16x32_bf16(a0, b1, acc[0][1], 0, 0, 0); \
        acc[0][2] = __builtin_amdgcn_mfma_f32_16x16x32_bf16(a0, b2, acc[0][2], 0, 0, 0); \
        acc[0][3] = __builtin_amdgcn_mfma_f32_16x16x32_bf16(a0, b3, acc[0][3], 0, 0, 0); \
        acc[1][0] = __builtin_amdgcn_mfma_f32_16x16x32_bf16(a1, b0, acc[1][0], 0, 0, 0); \
        acc[1][1] = __builtin_amdgcn_mfma_f32_16x16x32_bf16(a1, b1, acc[1][1], 0, 0, 0); \
        acc[1][2] = __builtin_amdgcn_mfma_f32_16x16x32_bf16(a1, b2, acc[1][2], 0, 0, 0); \
        acc[1][3] = __builtin_amdgcn_mfma_f32_16x16x32_bf16(a1, b3, acc[1][3], 0, 0, 0); \
    } \
} while (0)

// ---------------- GEMM1: e1g/g1g[p][n] = xb[idx[p]] @ W1[e] ----------------
__global__ __launch_bounds__(256)
void k6_gemm1(const unsigned short* __restrict__ xb, const unsigned short* __restrict__ W1t,
              const int* __restrict__ offs, const int* __restrict__ idx,
              unsigned short* __restrict__ e1g, unsigned short* __restrict__ g1g) {
    const int e = blockIdx.z;
    const int rowStart = offs[e] + blockIdx.y * 64;
    const int rowEnd = offs[e + 1];
    if (rowStart >= rowEnd) return;
    const int nt = blockIdx.x;

    __shared__ __align__(16) unsigned short A0[64 * 64], A1[64 * 64];     // 8 KB each
    __shared__ __align__(16) unsigned short B0[128 * 64], B1[128 * 64];   // 16 KB each
    __shared__ int rowIdxL[64];

    const int tid  = threadIdx.x;
    const int lane = tid & 63;
    const int wave = tid >> 6;
    const int quad = lane >> 4;
    const int l16  = lane & 15;
    const int wrow = (wave & 1) * 32;
    const int wcol = (wave >> 1) * 64;

    if (tid < 64) {
        int p = rowStart + tid;
        rowIdxL[tid] = idx[p < rowEnd ? p : rowEnd - 1];
    }
    __syncthreads();

    const unsigned short* aRow   = xb + (size_t)rowIdxL[tid & 63] * D_IN;
    const unsigned short* bPanel = W1t + ((((size_t)e * 8 + nt) * (D_IN / 32)) << 12);

    f32x4 acc[2][4];
    const f32x4 zf = {0.f, 0.f, 0.f, 0.f};
    #pragma unroll
    for (int r = 0; r < 2; r++)
        #pragma unroll
        for (int c = 0; c < 4; c++) acc[r][c] = zf;

    STAGE_A(A0, 0); STAGE_B(B0, 0);
    __syncthreads();
    for (int t = 0; t < STEPS1; t += 2) {
        STAGE_A(A1, t + 1); STAGE_B(B1, t + 1);   // prefetch next tile, then compute
        COMPUTE(A0, B0);
        __syncthreads();
        if (t + 2 < STEPS1) { STAGE_A(A0, t + 2); STAGE_B(B0, t + 2); }
        COMPUTE(A1, B1);
        __syncthreads();
    }

    // C/D: col = l16, row = quad*4 + q. Write raw bf16 + gelu'd bf16 (grouped rows).
    const int n0 = nt * 128;
    #pragma unroll
    for (int r = 0; r < 2; r++)
        #pragma unroll
        for (int q = 0; q < 4; q++) {
            int m = wrow + r * 16 + quad * 4 + q;
            int pp = rowStart + m;
            if (pp < rowEnd) {
                unsigned short* ep = e1g + (size_t)pp * D_OUT + n0 + wcol + l16;
                unsigned short* gp = g1g + (size_t)pp * D_OUT + n0 + wcol + l16;
                #pragma unroll
                for (int c = 0; c < 4; c++) {
                    unsigned short vb = f2b(acc[r][c][q]);
                    ep[c * 16] = vb;
                    float v = b2f(vb);
                    gp[c * 16] = f2b(v / (1.0f + __expf(-1.702f * v)));
                }
            }
        }
}

// ---------------- GEMM2: out0[idx[p]][n] = f32( g1g @ W2 + e1g ) ----------------
__global__ __launch_bounds__(256)
void k6_gemm2(const unsigned short* __restrict__ g1g, const unsigned short* __restrict__ e1g,
              const unsigned short* __restrict__ W2t,
              const int* __restrict__ offs, const int* __restrict__ idx,
              float* __restrict__ out0) {
    const int e = blockIdx.z;
    const int rowStart = offs[e] + blockIdx.y * 64;
    const int rowEnd = offs[e + 1];
    if (rowStart >= rowEnd) return;
    const int nt = blockIdx.x;

    __shared__ __align__(16) unsigned short A0[64 * 64], A1[64 * 64];
    __shared__ __align__(16) unsigned short B0[128 * 64], B1[128 * 64];
    __shared__ int rowIdxL[64];

    const int tid  = threadIdx.x;
    const int lane = tid & 63;
    const int wave = tid >> 6;
    const int quad = lane >> 4;
    const int l16  = lane & 15;
    const int wrow = (wave & 1) * 32;
    const int wcol = (wave >> 1) * 64;

    if (tid < 64) {
        int p = rowStart + tid;
        int ps = p < rowEnd ? p : rowEnd - 1;
        rowIdxL[tid] = idx[ps];
    }
    __syncthreads();

    int ap = rowStart + (tid & 63);
    const unsigned short* aRow   = g1g + (size_t)(ap < rowEnd ? ap : rowEnd - 1) * D_OUT;
    const unsigned short* bPanel = W2t + ((((size_t)e * 8 + nt) * (D_OUT / 32)) << 12);

    f32x4 acc[2][4];
    const f32x4 zf = {0.f, 0.f, 0.f, 0.f};
    #pragma unroll
    for (int r = 0; r < 2; r++)
        #pragma unroll
        for (int c = 0; c < 4; c++) acc[r][c] = zf;

    STAGE_A(A0, 0); STAGE_B(B0, 0);
    __syncthreads();
    for (int t = 0; t < STEPS2; t += 2) {
        STAGE_A(A1, t + 1); STAGE_B(B1, t + 1);
        COMPUTE(A0, B0);
        __syncthreads();
        if (t + 2 < STEPS2) { STAGE_A(A0, t + 2); STAGE_B(B0, t + 2); }
        COMPUTE(A1, B1);
        __syncthreads();
    }

    // epilogue: s = acc + e1 (residual), scatter f32 to original rows
    const int n0 = nt * 128;
    #pragma unroll
    for (int r = 0; r < 2; r++)
        #pragma unroll
        for (int q = 0; q < 4; q++) {
            int m = wrow + r * 16 + quad * 4 + q;
            int pp = rowStart + m;
            if (pp < rowEnd) {
                const unsigned short* ep = e1g + (size_t)pp * D_OUT + n0 + wcol + l16;
                float* op = out0 + (size_t)rowIdxL[m] * D_OUT + n0 + wcol + l16;
                #pragma unroll
                for (int c = 0; c < 4; c++)
                    op[c * 16] = acc[r][c][q] + b2f(ep[c * 16]);
            }
        }
}

// ---------------- LN + L2, in place on out0; one wave per row ----------------
__global__ __launch_bounds__(256)
void k4_ln(float* __restrict__ out0, const int* __restrict__ cls,
           const float* __restrict__ gam, const float* __restrict__ bet) {
    const int wave = threadIdx.x >> 6;
    const int lane = threadIdx.x & 63;
    const int b = blockIdx.x * 4 + wave;
    const int e = cls[b];

    float* row = out0 + (size_t)b * D_OUT + lane * 16;
    float v[16];
    #pragma unroll
    for (int j = 0; j < 4; j++) {
        float4 t = *(const float4*)(row + j * 4);
        v[j*4] = t.x; v[j*4+1] = t.y; v[j*4+2] = t.z; v[j*4+3] = t.w;
    }

    float sum = 0.f, sq = 0.f;
    #pragma unroll
    for (int j = 0; j < 16; j++) { sum += v[j]; sq += v[j] * v[j]; }
    #pragma unroll
    for (int o = 32; o; o >>= 1) { sum += __shfl_xor(sum, o, 64); sq += __shfl_xor(sq, o, 64); }
    float mean = sum * (1.0f / 1024.0f);
    float var = sq * (1.0f / 1024.0f) - mean * mean;
    float inv = rsqrtf(var + LN_EPS);

    const float* gp = gam + (size_t)e * D_OUT + lane * 16;
    const float* bp = bet + (size_t)e * D_OUT + lane * 16;
    float y[16]; float y2 = 0.f;
    #pragma unroll
    for (int j = 0; j < 16; j++) {
        y[j] = (v[j] - mean) * inv * gp[j] + bp[j];
        y2 += y[j] * y[j];
    }
    #pragma unroll
    for (int o = 32; o; o >>= 1) y2 += __shfl_xor(y2, o, 64);
    float rn = rsqrtf(y2);

    #pragma unroll
    for (int j = 0; j < 4; j++) {
        float4 t = { y[j*4] * rn, y[j*4+1] * rn, y[j*4+2] * rn, y[j*4+3] * rn };
        *(float4*)(row + j * 4) = t;
    }
}

// ---------------- launch: 4 dispatches total ----------------
extern "C" void kernel_launch(void* const* d_in, const int* in_sizes, int n_in,
                              void* d_out, int out_size, void* d_ws, size_t ws_size,
                              hipStream_t stream) {
    const float* x   = (const float*)d_in[0];
    const float* lg  = (const float*)d_in[1];
    const float* W1  = (const float*)d_in[2];
    const float* W2  = (const float*)d_in[3];
    const float* gam = (const float*)d_in[4];
    const float* bet = (const float*)d_in[5];
    float* out0 = (float*)d_out;
    float* out1 = out0 + (size_t)BSAMP * D_OUT;

    // ws layout: [0,64K) control | W1t 15.7M | W2t 21M | e1g 8.4M | g1g 8.4M | xb 6.3M
    //            total ~60 MB.
    char* ws = (char*)d_ws;
    int* offs = (int*)ws;              // 16
    int* cls  = offs + 16;             // 4096
    int* idx  = cls + BSAMP;           // 4096
    unsigned short* W1t = (unsigned short*)(ws + 65536);
    unsigned short* W2t = W1t + (size_t)NEXP * D_IN * D_OUT;
    unsigned short* e1g = W2t + (size_t)NEXP * D_OUT * D_OUT;
    unsigned short* g1g = e1g + (size_t)BSAMP * D_OUT;
    unsigned short* xb  = g1g + (size_t)BSAMP * D_OUT;

    // 1: routing + W1/W2 convert + x convert, all concurrent in one dispatch
    k7_prep<<<NB_PREP, 256, 0, stream>>>(lg, x, W1, W2, out1, cls, idx, offs,
                                         xb, W1t, W2t);

    // 2: GEMM1 (writes raw e1 and gelu(e1))
    dim3 g1(8, 64, NEXP);
    k6_gemm1<<<g1, 256, 0, stream>>>(xb, W1t, offs, idx, e1g, g1g);

    // 3: GEMM2 (+residual, scatter to original rows)
    dim3 g2(8, 64, NEXP);
    k6_gemm2<<<g2, 256, 0, stream>>>(g1g, e1g, W2t, offs, idx, out0);

    // 4: LayerNorm + L2 normalize
    k4_ln<<<BSAMP / 4, 256, 0, stream>>>(out0, cls, gam, bet);
}